// Round 6
// baseline (956.561 us; speedup 1.0000x reference)
//
#include <hip/hip_runtime.h>
#include <math.h>

#define Nn 1024
#define Ee 4
#define Uu 32
#define STAGE_M 256    // m elements staged per stage (32 KiB tile)
#define BLOCK_ROWS 16  // 4 waves x 4 rows

// ---------------------------------------------------------------------------
// pre-kernel: grid (128, 5), block 256. blockIdx.y = e (0..3 edge types,
// 4 = residual W2/b2).
//   e<4 : hpre_t[b][e][u][n] = sum_f ann[b,n,f]*Wa[e,f,u] + ba[e,u]  (u-major!)
//   e==4: res[b][n][u]       = sum_f ann[b,n,f]*W2[f,u]  + b2[u]
// ---------------------------------------------------------------------------
template <int F, int FA>
__global__ __launch_bounds__(256) void pre_kernel(
    const float* __restrict__ annA, const float* __restrict__ annB,
    const float* __restrict__ Wa, const float* __restrict__ ba,
    const float* __restrict__ W2, const float* __restrict__ b2,
    float* __restrict__ hpre_t, float* __restrict__ res)
{
    const int e = blockIdx.y;            // 0..4
    __shared__ float wlds[F * Uu];
    __shared__ float blds[Uu];
    const int tid = threadIdx.x;
    const float* wsrc = (e < 4) ? (Wa + (size_t)e * F * Uu) : W2;
    const float* bsrc = (e < 4) ? (ba + (size_t)e * Uu) : b2;
    for (int i = tid; i < F * Uu; i += 256) wlds[i] = wsrc[i];
    if (tid < Uu) blds[tid] = bsrc[tid];
    __syncthreads();

    const int g = blockIdx.x * 256 + tid;   // flat row in [0, B*N)
    const int b = g >> 10;
    const int n = g & 1023;

    float4 a4[F / 4];
    {
        const float4* rA = (const float4*)(annA + (size_t)g * FA);
#pragma unroll
        for (int i = 0; i < FA / 4; ++i) a4[i] = rA[i];
        if constexpr (F > FA) {
            const float4* rB = (const float4*)(annB + (size_t)g * (F - FA));
#pragma unroll
            for (int i = 0; i < (F - FA) / 4; ++i) a4[FA / 4 + i] = rB[i];
        }
    }

    float4 acc[8];
    const float4* bb = (const float4*)blds;
#pragma unroll
    for (int uq = 0; uq < 8; ++uq) acc[uq] = bb[uq];
    const float4* w4 = (const float4*)wlds;
#pragma unroll
    for (int f4 = 0; f4 < F / 4; ++f4) {
        const float4 av = a4[f4];
#pragma unroll
        for (int c = 0; c < 4; ++c) {
            const float s = (c == 0) ? av.x : (c == 1) ? av.y : (c == 2) ? av.z : av.w;
#pragma unroll
            for (int uq = 0; uq < 8; ++uq) {
                const float4 w = w4[(f4 * 4 + c) * 8 + uq];  // uniform -> broadcast
                acc[uq].x = fmaf(s, w.x, acc[uq].x);
                acc[uq].y = fmaf(s, w.y, acc[uq].y);
                acc[uq].z = fmaf(s, w.z, acc[uq].z);
                acc[uq].w = fmaf(s, w.w, acc[uq].w);
            }
        }
    }
    if (e < 4) {
        float* dst = hpre_t + ((size_t)(b * 4 + e) * Uu) * Nn + n;  // [b][e][u][n]
#pragma unroll
        for (int uq = 0; uq < 8; ++uq) {
            dst[(uq * 4 + 0) * Nn] = acc[uq].x;
            dst[(uq * 4 + 1) * Nn] = acc[uq].y;
            dst[(uq * 4 + 2) * Nn] = acc[uq].z;
            dst[(uq * 4 + 3) * Nn] = acc[uq].w;
        }
    } else {
        float4* dst = (float4*)(res + (size_t)g * Uu);
#pragma unroll
        for (int uq = 0; uq < 8; ++uq) dst[uq] = acc[uq];
    }
}

// ---------------------------------------------------------------------------
// main kernel: out[b][n][u] = tanh( sum_e sum_m adj[b,e,n,m]*h_pre[b,e,m,u]
//                                   + res[b,n,u] )
// Occupancy-first structure: 256 thr (4 waves x 4 rows = 16 rows/block),
// 32 KiB h stage tile -> 5 blocks/CU (LDS 5x32=160 KiB), 20 waves/CU.
// With 20 waves each holding ~1 KB of next-chunk adj loads, in-flight
// bytes/CU ~ 20 KB > the ~9.2 KB needed to hide HBM latency -> TLP alone
// saturates BW; no fragile explicit pipelining.
// 16 stages = e x 4 m-quarters. Each stage: glds h tile (linear, conflict-
// free), barrier, then 4 barrier-free chunks of 64 m (adj global->reg,
// h ds_read_b128 at the 8-dword/bank floor, 128 FMA/lane), barrier.
// Per-b blocks map to one XCD (swizzle), so h[b] (512 KB) stays L2-resident.
// ---------------------------------------------------------------------------
__global__ __launch_bounds__(256, 5) void gcn_main_kernel(
    const float* __restrict__ adj,     // [B,E,N,N]
    const float* __restrict__ hpre_t,  // [B,E,U,N]
    const float* __restrict__ res,     // [B,N,U]
    float* __restrict__ out)           // [B,N,U]
{
    __shared__ float hlds[Uu * STAGE_M];   // 32 KiB, [u][m] linear

    const int bid = blockIdx.x;                       // 2048 blocks
    const int swz = (bid & 7) * 256 + (bid >> 3);     // XCD-aware, bijective
    const int b = swz >> 6;                           // 64 blocks per b, one XCD
    const int n0 = (swz & 63) * BLOCK_ROWS;
    const int tid = threadIdx.x;
    const int w = tid >> 6;       // wave 0..3
    const int lane = tid & 63;
    const int gu = lane >> 4;     // u-octet 0..3
    const int ms = lane & 15;     // m-subslot 0..15
    const int wrow = n0 + w * 4;  // 4 rows per wave

    const float* adjb = adj + (size_t)b * Ee * Nn * Nn;
    const float* hpb  = hpre_t + (size_t)b * Ee * Uu * Nn;

    float acc[4][8];
#pragma unroll
    for (int r = 0; r < 4; ++r)
#pragma unroll
        for (int j = 0; j < 8; ++j) acc[r][j] = 0.f;

    for (int s = 0; s < 16; ++s) {
        const int e = s >> 2;
        const int m0 = (s & 3) * STAGE_M;

        // ---- stage load: wave w brings u-rows [w*8, w*8+8) of the h tile ----
        {
            const float* hsrc = hpb + ((size_t)e * Uu + w * 8) * Nn + m0 + lane * 4;
#pragma unroll
            for (int ur = 0; ur < 8; ++ur) {
                __builtin_amdgcn_global_load_lds(
                    (const __attribute__((address_space(1))) void*)(hsrc + (size_t)ur * Nn),
                    (__attribute__((address_space(3))) void*)(&hlds[(w * 8 + ur) * STAGE_M]),
                    16, 0, 0);
            }
        }
        __syncthreads();   // per-stage drain; overlapped by 4 other blocks/CU

        // ---- barrier-free compute stretch: 4 chunks of 64 m ----
#pragma unroll
        for (int c = 0; c < 4; ++c) {
            const float* ap = adjb + ((size_t)e * Nn + wrow) * Nn + m0 + c * 64 + ms * 4;
            float4 av[4];
#pragma unroll
            for (int r = 0; r < 4; ++r) av[r] = *(const float4*)(ap + (size_t)r * Nn);
#pragma unroll
            for (int j = 0; j < 8; ++j) {
                const float4 hv = *(const float4*)(&hlds[(gu * 8 + j) * STAGE_M + c * 64 + ms * 4]);
#pragma unroll
                for (int r = 0; r < 4; ++r) {
                    float t0 = fmaf(av[r].x, hv.x, acc[r][j]);
                    t0 = fmaf(av[r].y, hv.y, t0);
                    t0 = fmaf(av[r].z, hv.z, t0);
                    acc[r][j] = fmaf(av[r].w, hv.w, t0);
                }
            }
        }
        __syncthreads();   // last ds_reads done before next stage overwrites hlds
    }

    // reduce partial sums across the 16 ms lanes (lane bits 0..3)
#pragma unroll
    for (int r = 0; r < 4; ++r)
#pragma unroll
        for (int j = 0; j < 8; ++j) {
            float v = acc[r][j];
            v += __shfl_xor(v, 1);
            v += __shfl_xor(v, 2);
            v += __shfl_xor(v, 4);
            v += __shfl_xor(v, 8);
            acc[r][j] = v;
        }

    // epilogue: lane ms==r writes row wrow+r (static acc indexing via unroll)
#pragma unroll
    for (int r = 0; r < 4; ++r) {
        if (ms == r) {
            const int n = wrow + r;
            const float* rp = res + ((size_t)b * Nn + n) * Uu + gu * 8;
            float* op = out + ((size_t)b * Nn + n) * Uu + gu * 8;
            const float4 r0 = *(const float4*)(rp);
            const float4 r1 = *(const float4*)(rp + 4);
            float4 o0, o1;
            o0.x = tanhf(acc[r][0] + r0.x);
            o0.y = tanhf(acc[r][1] + r0.y);
            o0.z = tanhf(acc[r][2] + r0.z);
            o0.w = tanhf(acc[r][3] + r0.w);
            o1.x = tanhf(acc[r][4] + r1.x);
            o1.y = tanhf(acc[r][5] + r1.y);
            o1.z = tanhf(acc[r][6] + r1.z);
            o1.w = tanhf(acc[r][7] + r1.w);
            *(float4*)(op) = o0;
            *(float4*)(op + 4) = o1;
        }
    }
}

extern "C" void kernel_launch(void* const* d_in, const int* in_sizes, int n_in,
                              void* d_out, int out_size, void* d_ws, size_t ws_size,
                              hipStream_t stream)
{
    const float* n_tensor = (const float*)d_in[0];  // [32,1024,32]
    const float* adj      = (const float*)d_in[1];  // [32,4,1024,1024]
    const float* W_adj0   = (const float*)d_in[2];  // [4,32,32]
    const float* b_adj0   = (const float*)d_in[3];  // [4,32]
    const float* W2_0     = (const float*)d_in[4];  // [32,32]
    const float* b2_0     = (const float*)d_in[5];  // [32]
    const float* W_adj1   = (const float*)d_in[6];  // [4,64,32]
    const float* b_adj1   = (const float*)d_in[7];  // [4,32]
    const float* W2_1     = (const float*)d_in[8];  // [64,32]
    const float* b2_1     = (const float*)d_in[9];  // [32]
    float* outp = (float*)d_out;

    float* ws   = (float*)d_ws;
    float* hpre = ws;                            // 16 MiB
    float* resb = ws + (size_t)4 * 1024 * 1024;  // 4 MiB
    float* h0   = ws + (size_t)5 * 1024 * 1024;  // 4 MiB

    dim3 pre_grid(128, 5);

    // layer 0 (F = 32)
    pre_kernel<32, 32><<<pre_grid, 256, 0, stream>>>(n_tensor, nullptr, W_adj0, b_adj0,
                                                     W2_0, b2_0, hpre, resb);
    gcn_main_kernel<<<2048, 256, 0, stream>>>(adj, hpre, resb, h0);

    // layer 1 (F = 64, ann = concat(n_tensor, h0))
    pre_kernel<64, 32><<<pre_grid, 256, 0, stream>>>(n_tensor, h0, W_adj1, b_adj1,
                                                     W2_1, b2_1, hpre, resb);
    gcn_main_kernel<<<2048, 256, 0, stream>>>(adj, hpre, resb, outp);
}